// Round 3
// baseline (126.345 us; speedup 1.0000x reference)
//
#include <hip/hip_runtime.h>

// COO SpMM: out[r,:] = sum_e vals[e] * seq[cols[e],:], rows sorted.
// N=50000, E=1.25M, D=64, fp32 in/out.
//
// R1: 256B gathers, atomic flush             -> 56.6 us
// R2: deep double-buffer                     -> 66.5 us FAIL
// R3: interleaved streams + dword atomics    -> 270 us FAIL
// R4: float4 + ownership, scalar meta        -> 60 us
// R5: coalesced meta, 16x1KB gathers, RPS=2  -> 53 us (3.4 TB/s, occ 29%)
// R6: RPS=1, oversubscribed, depth 8         -> ~41 us (~3.6 TB/s fetch path)
// R7: bf16 gather table (6.4 MB, 128B/row = 1 line/edge). harness 98.6 us
//     (~45 us = 256MB workspace re-poison fill; spmm ~41, prep ~8.)
// R8: concurrent feature-split (seqt[2][N][64B], half=blockIdx&1) -> 111 FAIL.
//     Post-mortem: residency relied on blockIdx->XCD parity staying clean;
//     any phase-mixing on an XCD restores the 6.4MB working set. And 64B
//     gathers over-fetch 2x per L2 miss (line=128B). Mechanism wrong.
// R9 (this): TEMPORAL column partitioning -- zero XCD-mapping assumptions.
//     spmm launched twice: phase0 edges with col<N/2, phase1 col>=N/2
//     (phase1 seeds acc from phase0's partial). Within a launch the GLOBAL
//     gather working set is one 3.2MB table half -> resident in every XCD's
//     4MiB L2 independently. Gathers keep R7's 128B/row one-line shape.
//     Streams (meta, partial, out) are non-temporal so they can't evict
//     the table. Cost: meta scanned 2x (+10MB), partial RMW (+25.6MB).

#define WPB 4               // waves per 256-thread block

typedef float f32x4 __attribute__((ext_vector_type(4)));

// Merged prep:
//   blocks [0, cvt_blocks):  fp32 seq -> packed bf16 seqb[N][16 x uint2]
//   blocks [cvt_blocks, ..): row_start[t] = first edge e with rows[e] >= t
__global__ __launch_bounds__(256) void prep_kernel(
    const float4* __restrict__ seq,       // [N*16] float4 (= [N][64] fp32)
    uint2*        __restrict__ seqb,      // [N][16] uint2 (128 B per node)
    const int*    __restrict__ rows,
    int*          __restrict__ row_start,
    int n_nodes, int n_edges, int cvt_blocks)
{
    if ((int)blockIdx.x < cvt_blocks) {
        const int t = blockIdx.x * 256 + threadIdx.x;   // one float4 -> one uint2
        if (t >= n_nodes * 16) return;
        const float4 f = seq[t];
        const unsigned ux = __float_as_uint(f.x), uy = __float_as_uint(f.y);
        const unsigned uz = __float_as_uint(f.z), uw = __float_as_uint(f.w);
        const unsigned bx = (ux + 0x7FFFu + ((ux >> 16) & 1u)) >> 16;
        const unsigned by = (uy + 0x7FFFu + ((uy >> 16) & 1u)) >> 16;
        const unsigned bz = (uz + 0x7FFFu + ((uz >> 16) & 1u)) >> 16;
        const unsigned bw = (uw + 0x7FFFu + ((uw >> 16) & 1u)) >> 16;
        uint2 o;
        o.x = bx | (by << 16);
        o.y = bz | (bw << 16);
        seqb[t] = o;                                    // same layout as input
    } else {
        const int e = (blockIdx.x - cvt_blocks) * 256 + threadIdx.x;
        if (e >= n_edges) return;
        const int r    = rows[e];
        const int prev = (e == 0) ? -1 : rows[e - 1];
        for (int t = prev + 1; t <= r; ++t) row_start[t] = e;
        if (e == n_edges - 1)
            for (int t = r + 1; t <= n_nodes; ++t) row_start[t] = n_edges;
    }
}

// One phase of the column-partitioned SpMM.
// Processes edges with clo <= col < chi. ACC=1: seed acc from out (partial).
template <int ACC>
__global__ __launch_bounds__(256) void spmm_kernel(
    const uint2* __restrict__ seqb,       // [N][16] uint2 packed bf16
    const float* __restrict__ vals,       // [E]
    const int*   __restrict__ cols,       // [E]
    const int*   __restrict__ row_start,  // [N+1]
    float*       __restrict__ out,        // [N, 64] fp32
    int n_nodes, int n_edges, int clo, int chi)
{
    const int lane = threadIdx.x & 63;
    const int sub  = lane >> 4;           // 16-lane sub-wave id (0..3)
    const int fl   = lane & 15;           // feature quad: floats 4*fl..4*fl+3
    const int wave = blockIdx.x * WPB + (threadIdx.x >> 6);

    const int r = wave * 4 + sub;         // one row per sub
    if (wave * 4 >= n_nodes) return;      // wave-uniform exit
    const bool valid = (r < n_nodes);

    int e = 0, e_end = 0;
    if (valid) {
        e     = row_start[r];
        e_end = row_start[r + 1];
    }

    // Seed from the phase-0 partial (nt: don't let it evict the table).
    // Kernel boundary orders this after phase 0's stores.
    float4 acc = make_float4(0.f, 0.f, 0.f, 0.f);
    if (ACC && valid) {
        const f32x4 p = __builtin_nontemporal_load(
            (const f32x4*)out + ((r << 4) + fl));
        acc.x = p.x; acc.y = p.y; acc.z = p.z; acc.w = p.w;
    }

    while (__any(e < e_end)) {
        // coalesced metadata: next 16 edges of this sub (streamed, nt)
        int cidx = e + fl;
        cidx = (cidx < 0) ? 0 : (cidx >= n_edges ? n_edges - 1 : cidx);
        const int   c = __builtin_nontemporal_load(cols + cidx);
        const float v = __builtin_nontemporal_load(vals + cidx);

        // up to 16 independent 128B-row gathers from the L2-resident
        // 3.2 MB half-table (plain cached loads)
        uint2 x[16];
#pragma unroll
        for (int u = 0; u < 16; ++u) {
            const int cu = __shfl(c, (sub << 4) | u);   // sub-local broadcast
            if ((e + u < e_end) & (cu >= clo) & (cu < chi))
                x[u] = seqb[(cu << 4) + fl];            // 8 B: 4 bf16 feats
        }
#pragma unroll
        for (int u = 0; u < 16; ++u) {
            const int cu = __shfl(c, (sub << 4) | u);
            const float vu = __shfl(v, (sub << 4) | u);
            if ((e + u < e_end) & (cu >= clo) & (cu < chi)) {
                const float f0 = __uint_as_float(x[u].x << 16);
                const float f1 = __uint_as_float(x[u].x & 0xFFFF0000u);
                const float f2 = __uint_as_float(x[u].y << 16);
                const float f3 = __uint_as_float(x[u].y & 0xFFFF0000u);
                acc.x = fmaf(vu, f0, acc.x);
                acc.y = fmaf(vu, f1, acc.y);
                acc.z = fmaf(vu, f2, acc.z);
                acc.w = fmaf(vu, f3, acc.w);
            }
        }
        e += 16;
    }

    // one 16 B nt-store per lane; 16 lanes = contiguous 256 B row.
    // Phase 0 also zeroes empty rows.
    if (valid) {
        f32x4 o;
        o.x = acc.x; o.y = acc.y; o.z = acc.z; o.w = acc.w;
        __builtin_nontemporal_store(o, (f32x4*)out + ((r << 4) + fl));
    }
}

extern "C" void kernel_launch(void* const* d_in, const int* in_sizes, int n_in,
                              void* d_out, int out_size, void* d_ws, size_t ws_size,
                              hipStream_t stream) {
    const float* seq  = (const float*)d_in[0];
    const float* vals = (const float*)d_in[1];
    const int*   rows = (const int*)d_in[2];
    const int*   cols = (const int*)d_in[3];
    float*       out  = (float*)d_out;

    const int n_edges = in_sizes[1];            // E
    const int n_nodes = out_size / 64;          // N (out is [1,N,64])

    // ws layout: [row_start: (N+1) ints][pad to 256][seqb: N*128 B]
    int*   row_start = (int*)d_ws;
    size_t off       = (((size_t)(n_nodes + 1) * 4 + 255) / 256) * 256;
    uint2* seqb      = (uint2*)((char*)d_ws + off);

    {
        const int cvt_blocks = (n_nodes * 16 + 255) / 256;
        const int rp_blocks  = (n_edges + 255) / 256;
        prep_kernel<<<cvt_blocks + rp_blocks, 256, 0, stream>>>(
            (const float4*)seq, seqb, rows, row_start,
            n_nodes, n_edges, cvt_blocks);
    }
    {
        const int waves  = (n_nodes + 3) / 4;   // one row per 16-lane sub
        const int blocks = (waves + WPB - 1) / WPB;
        const int nhalf  = n_nodes >> 1;
        spmm_kernel<0><<<blocks, 256, 0, stream>>>(
            seqb, vals, cols, row_start, out, n_nodes, n_edges, 0, nhalf);
        spmm_kernel<1><<<blocks, 256, 0, stream>>>(
            seqb, vals, cols, row_start, out, n_nodes, n_edges, nhalf, n_nodes);
    }
}

// Round 4
// 102.977 us; speedup vs baseline: 1.2269x; 1.2269x over previous
//
#include <hip/hip_runtime.h>

// COO SpMM: out[r,:] = sum_e vals[e] * seq[cols[e],:], rows sorted.
// N=50000, E=1.25M, D=64, fp32 in/out.
//
// R1: 256B gathers, atomic flush             -> 56.6 us
// R2: deep double-buffer                     -> 66.5 us FAIL
// R3: interleaved streams + dword atomics    -> 270 us FAIL
// R4: float4 + ownership, scalar meta        -> 60 us
// R5: coalesced meta, 16x1KB gathers, RPS=2  -> 53 us (3.4 TB/s, occ 29%)
// R6: RPS=1, oversubscribed, depth 8         -> ~41 us (~3.6 TB/s fetch path)
// R7: bf16 gather table (6.4 MB, 128B/row = 1 line/edge). harness 98.6 us
//     (~45 us = 256MB workspace re-poison fill; spmm ~41, prep ~8.)
// R8: concurrent feature-split halves        -> 111 FAIL (XCD parity myth)
// R9: temporal column partition (2 phases)   -> 126 FAIL. KEY EVIDENCE:
//     each phase ~37 us with HALF the gather bytes; plus R6->R7 halved
//     bytes with no gain. Gather BYTES are not the bottleneck; the EDGE
//     SCAN is (vmem issue rate + meta->gather latency chain per iter).
// R10 (this): attack the scan, keep bytes at 128B/edge.
//     a) 8-lane subs x dwordx4 (16B/lane): one gather instr = 8 rows
//        (8 lines) vs 4 -> vmem instrs per 64 edges: 18 -> 10.
//     b) meta software prefetch (load chunk i+1 before gathers of chunk i)
//        -> per-iteration chain = gather latency only.
//     c) single-pass dataflow (R7 style), nt meta/out, VGPR ~60 so
//        8 waves/SIMD stay resident.

#define WPB 4               // waves per 256-thread block

typedef float f32x4 __attribute__((ext_vector_type(4)));

// Merged prep:
//   blocks [0, cvt_blocks):  fp32 seq -> packed bf16 seqb[N][16 x uint2]
//   blocks [cvt_blocks, ..): row_start[t] = first edge e with rows[e] >= t
__global__ __launch_bounds__(256) void prep_kernel(
    const f32x4* __restrict__ seq,        // [N*16] float4 (= [N][64] fp32)
    uint2*       __restrict__ seqb,       // [N][16] uint2 (128 B per node)
    const int*   __restrict__ rows,
    int*         __restrict__ row_start,
    int n_nodes, int n_edges, int cvt_blocks)
{
    if ((int)blockIdx.x < cvt_blocks) {
        const int t = blockIdx.x * 256 + threadIdx.x;   // one float4 -> one uint2
        if (t >= n_nodes * 16) return;
        const f32x4 f = __builtin_nontemporal_load(seq + t);  // stream, don't pollute L2
        const unsigned ux = __float_as_uint(f.x), uy = __float_as_uint(f.y);
        const unsigned uz = __float_as_uint(f.z), uw = __float_as_uint(f.w);
        const unsigned bx = (ux + 0x7FFFu + ((ux >> 16) & 1u)) >> 16;
        const unsigned by = (uy + 0x7FFFu + ((uy >> 16) & 1u)) >> 16;
        const unsigned bz = (uz + 0x7FFFu + ((uz >> 16) & 1u)) >> 16;
        const unsigned bw = (uw + 0x7FFFu + ((uw >> 16) & 1u)) >> 16;
        uint2 o;
        o.x = bx | (by << 16);
        o.y = bz | (bw << 16);
        seqb[t] = o;                      // plain store: warms L2 with the table
    } else {
        const int e = (blockIdx.x - cvt_blocks) * 256 + threadIdx.x;
        if (e >= n_edges) return;
        const int r    = rows[e];
        const int prev = (e == 0) ? -1 : rows[e - 1];
        for (int t = prev + 1; t <= r; ++t) row_start[t] = e;
        if (e == n_edges - 1)
            for (int t = r + 1; t <= n_nodes; ++t) row_start[t] = n_edges;
    }
}

__global__ __launch_bounds__(256) void spmm_kernel(
    const uint4* __restrict__ seqb,       // [N][8] uint4 packed bf16 (128 B/row)
    const float* __restrict__ vals,       // [E]
    const int*   __restrict__ cols,       // [E]
    const int*   __restrict__ row_start,  // [N+1]
    float*       __restrict__ out,        // [N, 64] fp32
    int n_nodes, int n_edges)
{
    const int lane = threadIdx.x & 63;
    const int sub  = lane >> 3;           // 8-lane sub-wave id (0..7)
    const int fl   = lane & 7;            // 16B chunk of the row: feats 8*fl..8*fl+7
    const int wave = blockIdx.x * WPB + (threadIdx.x >> 6);

    const int r = wave * 8 + sub;         // one row per sub
    if (wave * 8 >= n_nodes) return;      // wave-uniform exit
    const bool valid = (r < n_nodes);

    int e = 0, e_end = 0;
    if (valid) {
        e     = row_start[r];
        e_end = row_start[r + 1];
    }

    float acc[8] = {0.f, 0.f, 0.f, 0.f, 0.f, 0.f, 0.f, 0.f};

    // meta for the FIRST chunk (8 edges of this sub, lanes coalesced)
    int   c_cur;
    float v_cur;
    {
        int cidx = e + fl;
        if (cidx >= n_edges) cidx = n_edges - 1;
        c_cur = __builtin_nontemporal_load(cols + cidx);
        v_cur = __builtin_nontemporal_load(vals + cidx);
    }

    while (__any(e < e_end)) {
        // prefetch NEXT chunk's meta before gathers: keeps meta latency
        // out of the dependency chain (address is induction-only)
        int nidx = e + 8 + fl;
        if (nidx >= n_edges) nidx = n_edges - 1;
        const int   c_nxt = __builtin_nontemporal_load(cols + nidx);
        const float v_nxt = __builtin_nontemporal_load(vals + nidx);

        // 8 gathers, each instr covers 8 rows x 16 B = 8 lines; a sub's
        // 8 lanes together read one full 128 B row (1 line/edge, no waste)
        uint4 x[8];
#pragma unroll
        for (int u = 0; u < 8; ++u) {
            const int cu = __shfl(c_cur, (sub << 3) | u);   // sub-local bcast
            if (e + u < e_end)
                x[u] = seqb[(cu << 3) + fl];                // 16 B: 8 bf16 feats
        }
#pragma unroll
        for (int u = 0; u < 8; ++u) {
            const float vu = __shfl(v_cur, (sub << 3) | u);
            if (e + u < e_end) {
                const unsigned w0 = x[u].x, w1 = x[u].y, w2 = x[u].z, w3 = x[u].w;
                acc[0] = fmaf(vu, __uint_as_float(w0 << 16),         acc[0]);
                acc[1] = fmaf(vu, __uint_as_float(w0 & 0xFFFF0000u), acc[1]);
                acc[2] = fmaf(vu, __uint_as_float(w1 << 16),         acc[2]);
                acc[3] = fmaf(vu, __uint_as_float(w1 & 0xFFFF0000u), acc[3]);
                acc[4] = fmaf(vu, __uint_as_float(w2 << 16),         acc[4]);
                acc[5] = fmaf(vu, __uint_as_float(w2 & 0xFFFF0000u), acc[5]);
                acc[6] = fmaf(vu, __uint_as_float(w3 << 16),         acc[6]);
                acc[7] = fmaf(vu, __uint_as_float(w3 & 0xFFFF0000u), acc[7]);
            }
        }
        e += 8;
        c_cur = c_nxt;
        v_cur = v_nxt;
    }

    // two 16 B nt-stores per lane; a sub's 8 lanes = contiguous 256 B row.
    // Also zeroes empty rows.
    if (valid) {
        f32x4 o0, o1;
        o0.x = acc[0]; o0.y = acc[1]; o0.z = acc[2]; o0.w = acc[3];
        o1.x = acc[4]; o1.y = acc[5]; o1.z = acc[6]; o1.w = acc[7];
        f32x4* dst = (f32x4*)out + ((r << 4) + (fl << 1));
        __builtin_nontemporal_store(o0, dst);
        __builtin_nontemporal_store(o1, dst + 1);
    }
}

extern "C" void kernel_launch(void* const* d_in, const int* in_sizes, int n_in,
                              void* d_out, int out_size, void* d_ws, size_t ws_size,
                              hipStream_t stream) {
    const float* seq  = (const float*)d_in[0];
    const float* vals = (const float*)d_in[1];
    const int*   rows = (const int*)d_in[2];
    const int*   cols = (const int*)d_in[3];
    float*       out  = (float*)d_out;

    const int n_edges = in_sizes[1];            // E
    const int n_nodes = out_size / 64;          // N (out is [1,N,64])

    // ws layout: [row_start: (N+1) ints][pad to 256][seqb: N*128 B]
    int*   row_start = (int*)d_ws;
    size_t off       = (((size_t)(n_nodes + 1) * 4 + 255) / 256) * 256;
    uint2* seqb      = (uint2*)((char*)d_ws + off);

    {
        const int cvt_blocks = (n_nodes * 16 + 255) / 256;
        const int rp_blocks  = (n_edges + 255) / 256;
        prep_kernel<<<cvt_blocks + rp_blocks, 256, 0, stream>>>(
            (const f32x4*)seq, seqb, rows, row_start,
            n_nodes, n_edges, cvt_blocks);
    }
    {
        const int waves  = (n_nodes + 7) / 8;   // one row per 8-lane sub
        const int blocks = (waves + WPB - 1) / WPB;
        spmm_kernel<<<blocks, 256, 0, stream>>>(
            (const uint4*)seqb, vals, cols, row_start, out,
            n_nodes, n_edges);
    }
}